// Round 9
// baseline (150.595 us; speedup 1.0000x reference)
//
#include <hip/hip_runtime.h>

// Problem dims (hardcoded per reference setup_inputs):
//   x:   (8, 64, 64, 64)   fp32
//   ref: (8, 64, 128, 128) fp32
//   out: (8, 64, 128, 128) fp32
#define B   8
#define C   64
#define HI  64
#define WI  64
#define HO  128
#define WO  128

using short8 = __attribute__((ext_vector_type(8))) short;
using f32x4  = __attribute__((ext_vector_type(4))) float;
using i32x4  = __attribute__((ext_vector_type(4))) int;

__device__ __forceinline__ float relu(float v) { return v > 0.f ? v : 0.f; }

// pack two f32 -> bf16 pair (lo in bits [15:0], hi in bits [31:16]), RNE
__device__ __forceinline__ unsigned packbf(float lo, float hi) {
  unsigned ua = __float_as_uint(lo); ua += 0x7FFFu + ((ua >> 16) & 1u);
  unsigned ub = __float_as_uint(hi); ub += 0x7FFFu + ((ub >> 16) & 1u);
  return (ua >> 16) | (ub & 0xFFFF0000u);
}

// LDS-only barrier: orders LDS traffic (lgkmcnt) WITHOUT draining vmcnt.
// 0xc07f = vmcnt(63) | expcnt(7) | lgkmcnt(0). Safe: no intra-block global
// communication (out write-only; x/ref read-only). Prefetched register loads
// get compiler-inserted vmcnt waits at first use. sched_barrier(0) pins code
// motion (rule #18).
__device__ __forceinline__ void bar_lds() {
  __builtin_amdgcn_sched_barrier(0);
  __builtin_amdgcn_s_waitcnt(0xc07f);
  __builtin_amdgcn_s_barrier();
  __builtin_amdgcn_sched_barrier(0);
}

// ---------------------------------------------------------------------------
// Persistent-block pipelined kernel, 2 BLOCKS/CU (the round-9 change).
// 512 blocks x 512 threads; each block does 2 rows h = hbase, hbase+1 of
// batch b = bx&7 (XCD-affine). LDS = 76.8 KB -> 2 blocks/CU;
// __launch_bounds__(512,4) caps VGPR at 128 (16 waves/CU).
// A co-resident block computes while this one waits at barriers — the TLP
// that the 1-block/CU version lacked.
//
// LDS: y1cT [128 px][68 ch] f32; xPT/refPT [128 px][36 c2] u32 bf16-pairs;
//      resr [4][128][2] rolling gather rows; s_wcp/s_bs1/s_bs2.
// Gather chains (32 ref-channel loads, ascending — bit-exact round-0 lineage)
// are split into two 16-deep register batches: sum(b1) then reuse regs for
// b2 — identical addition order, half the VGPR.
// Pipeline: prologue(stage row hbase + gather rows hbase-1..hbase+1)
//   it=0: A(prefetch row hbase+1 + gather hbase+2 b1) C bar D E(write) bar
//   it=1: C bar D.
// ---------------------------------------------------------------------------
__global__ __launch_bounds__(512, 4) void k_all(
    const float* __restrict__ x,   const float* __restrict__ ref,
    const float* __restrict__ w1,  const float* __restrict__ c1b,
    const float* __restrict__ g1,  const float* __restrict__ b1v,
    const float* __restrict__ m1,  const float* __restrict__ v1,
    const float* __restrict__ w2,  const float* __restrict__ c2b,
    const float* __restrict__ g2,  const float* __restrict__ b2v,
    const float* __restrict__ m2,  const float* __restrict__ v2,
    float* __restrict__ out) {
  __shared__ __align__(16) float    y1cT[128 * 68];    // [px][ch]
  __shared__ __align__(16) unsigned xPT[128 * 36];     // [px][c2] bf16-pair
  __shared__ __align__(16) unsigned refPT[128 * 36];   // [px][c2] bf16-pair
  __shared__ __align__(16) float    resr[4][128][2];   // rolling gather rows
  __shared__ unsigned s_wcp[128];                      // wc0..3 + den nibbles
  __shared__ float    s_bs1[64];
  __shared__ float    s_bs2[64];

  const int bx  = blockIdx.x;
  const int b     = bx & 7;          // XCD-affine batch
  const int hbase = (bx >> 3) * 2;   // 0,2,...,126
  const int tid = threadIdx.x;

  const int wid  = tid >> 6;          // 0..7
  const int lane = tid & 63;
  const int wo = wid & 3, wp = wid >> 2;   // o-tile, px-half
  const int lq = lane >> 4, ln = lane & 15;
  const int ob = wo * 16 + lq * 4;
  const int ow = wo * 16 + ln;        // weight row for A-fragments

  // staging ownership (px-major)
  const int spx  = tid & 127;         // owned px
  const int sc2g = tid >> 7;          // c2 octet: c2 = sc2g*8 + c
  const int scol = spx & 63;          // x column
  const int ssel = spx >> 6;          // x row selector (0 -> rlo, 1 -> r1)

  // ---- weight fragment loads issued first (once per block) -----------------
  const float4 wa0 = *(const float4*)&w1[ow * 64 + lq * 8];
  const float4 wa1 = *(const float4*)&w1[ow * 64 + lq * 8 + 4];
  const float4 wa2 = *(const float4*)&w1[ow * 64 + 32 + lq * 8];
  const float4 wa3 = *(const float4*)&w1[ow * 64 + 32 + lq * 8 + 4];
  const float4 wb0 = *(const float4*)&w2[ow * 64 + lq * 8];
  const float4 wb1 = *(const float4*)&w2[ow * 64 + lq * 8 + 4];
  const float4 wb2 = *(const float4*)&w2[ow * 64 + 32 + lq * 8];
  const float4 wb3 = *(const float4*)&w2[ow * 64 + 32 + lq * 8 + 4];
  const float g1o = g1[ow], v1o = v1[ow];
  const float g2o = g2[ow], v2o = v2[ow];

  // ---------------- prologue: stage row hbase; gather hbase-1..hbase+1 ------
  const int grr = tid >> 7;                  // 0..3 (only 0..2 gather)
  const int gp = (tid & 127) >> 1, ghalf = tid & 1;
  {
    const int rlo0 = (hbase >= 1) ? ((hbase - 1) >> 1) : 0;
    int r10 = rlo0 + 1; if (r10 > HI - 1) r10 = HI - 1;

    float xv[16], rv[16];
    {
      const int xr = ssel ? r10 : rlo0;
      const float* xb = x + ((size_t)(b * C + sc2g * 16) * HI + xr) * WI + scol;
      const float* rb = ref + ((size_t)(b * C + sc2g * 16) * HO + hbase) * WO + spx;
#pragma unroll
      for (int c = 0; c < 8; ++c) {
        xv[2 * c]     = xb[(size_t)(2 * c) * (HI * WI)];
        xv[2 * c + 1] = xb[(size_t)(2 * c + 1) * (HI * WI)];
        rv[2 * c]     = rb[(size_t)(2 * c) * (HO * WO)];
        rv[2 * c + 1] = rb[(size_t)(2 * c + 1) * (HO * WO)];
      }
    }
    // gather rows hbase-1..hbase+1 -> slots 0..2 (threads 0..383, 1 chain ea.)
    // 32-deep ascending chain as two 16-deep register batches (bit-exact).
    float2 pg[16];
    bool gok = false;
    const float* gsp = nullptr;
    float sx = 0.f, sy = 0.f;
    if (tid < 384) {
      const int hh = hbase + grr - 1;
      if (hh >= 0 && hh < HO) {
        gok = true;
        gsp = ref + ((size_t)(b * C + ghalf) * HO + hh) * WO + 2 * gp;
#pragma unroll
        for (int k = 0; k < 16; ++k)        // batch 1 issue
          pg[k] = *(const float2*)&gsp[(size_t)(2 * k) * (HO * WO)];
      }
    }
    if (tid >= 448) {                        // biases (threads 448..511)
      const int t2 = tid - 448;
      float s = g1[t2] * rsqrtf(v1[t2] + 1e-5f);
      s_bs1[t2] = c1b[t2] * s + b1v[t2] - m1[t2] * s;
      s = g2[t2] * rsqrtf(v2[t2] + 1e-5f);
      s_bs2[t2] = c2b[t2] * s + b2v[t2] - m2[t2] * s;
    }
    {
      uint4 u0, u1, v0, v1q;
      u0.x = packbf(xv[0], xv[1]);  u0.y = packbf(xv[2], xv[3]);
      u0.z = packbf(xv[4], xv[5]);  u0.w = packbf(xv[6], xv[7]);
      u1.x = packbf(xv[8], xv[9]);  u1.y = packbf(xv[10], xv[11]);
      u1.z = packbf(xv[12], xv[13]); u1.w = packbf(xv[14], xv[15]);
      v0.x = packbf(rv[0], rv[1]);  v0.y = packbf(rv[2], rv[3]);
      v0.z = packbf(rv[4], rv[5]);  v0.w = packbf(rv[6], rv[7]);
      v1q.x = packbf(rv[8], rv[9]); v1q.y = packbf(rv[10], rv[11]);
      v1q.z = packbf(rv[12], rv[13]); v1q.w = packbf(rv[14], rv[15]);
      *(uint4*)&xPT[spx * 36 + sc2g * 8]       = u0;
      *(uint4*)&xPT[spx * 36 + sc2g * 8 + 4]   = u1;
      *(uint4*)&refPT[spx * 36 + sc2g * 8]     = v0;
      *(uint4*)&refPT[spx * 36 + sc2g * 8 + 4] = v1q;
    }
    if (gok) {                               // sum b1, issue+sum b2 (ascending)
#pragma unroll
      for (int k = 0; k < 16; ++k) { sx += pg[k].x; sy += pg[k].y; }
#pragma unroll
      for (int k = 0; k < 16; ++k)
        pg[k] = *(const float2*)&gsp[(size_t)(2 * (k + 16)) * (HO * WO)];
#pragma unroll
      for (int k = 0; k < 16; ++k) { sx += pg[k].x; sy += pg[k].y; }
    }
    if (tid < 384) {
      resr[grr][2 * gp][ghalf]     = sx;
      resr[grr][2 * gp + 1][ghalf] = sy;
    }
  }

  // pack weight fragments (loads long since landed; raw regs freed after)
  i32x4 fa0i, fa1i, fb0i, fb1i;
  {
    const float s1 = g1o * rsqrtf(v1o + 1e-5f);
    const float s2 = g2o * rsqrtf(v2o + 1e-5f);
    fa0i[0] = (int)packbf(wa0.x * s1, wa0.y * s1);
    fa0i[1] = (int)packbf(wa0.z * s1, wa0.w * s1);
    fa0i[2] = (int)packbf(wa1.x * s1, wa1.y * s1);
    fa0i[3] = (int)packbf(wa1.z * s1, wa1.w * s1);
    fa1i[0] = (int)packbf(wa2.x * s1, wa2.y * s1);
    fa1i[1] = (int)packbf(wa2.z * s1, wa2.w * s1);
    fa1i[2] = (int)packbf(wa3.x * s1, wa3.y * s1);
    fa1i[3] = (int)packbf(wa3.z * s1, wa3.w * s1);
    fb0i[0] = (int)packbf(wb0.x * s2, wb0.y * s2);
    fb0i[1] = (int)packbf(wb0.z * s2, wb0.w * s2);
    fb0i[2] = (int)packbf(wb1.x * s2, wb1.y * s2);
    fb0i[3] = (int)packbf(wb1.z * s2, wb1.w * s2);
    fb1i[0] = (int)packbf(wb2.x * s2, wb2.y * s2);
    fb1i[1] = (int)packbf(wb2.z * s2, wb2.w * s2);
    fb1i[2] = (int)packbf(wb3.x * s2, wb3.y * s2);
    fb1i[3] = (int)packbf(wb3.z * s2, wb3.w * s2);
  }
  const short8 fa0 = __builtin_bit_cast(short8, fa0i);
  const short8 fa1 = __builtin_bit_cast(short8, fa1i);
  const short8 fb0 = __builtin_bit_cast(short8, fb0i);
  const short8 fb1 = __builtin_bit_cast(short8, fb1i);
  bar_lds();   // prologue barrier (LDS-only)

  float bs1a[4], bs2a[4];
  *(float4*)bs1a = *(const float4*)&s_bs1[ob];
  *(float4*)bs2a = *(const float4*)&s_bs2[ob];

  // ---------------- 2-row pipeline ------------------------------------------
#pragma unroll
  for (int it = 0; it < 2; ++it) {
    const int h = hbase + it;
    const int rloc = (h >= 1) ? ((h - 1) >> 1) : 0;

    // ---- A: issue next row's loads into regs (it==0 only) ------------------
    float xv[16], rv[16];
    float2 g[16];
    bool gk = false;
    const float* gsp = nullptr;
    if (it == 0) {
      const int hn = h + 1;
      const int rlon = (hn - 1) >> 1;
      int r1n = rlon + 1; if (r1n > HI - 1) r1n = HI - 1;
      const int xr = ssel ? r1n : rlon;
      const float* xb = x + ((size_t)(b * C + sc2g * 16) * HI + xr) * WI + scol;
      const float* rb = ref + ((size_t)(b * C + sc2g * 16) * HO + hn) * WO + spx;
#pragma unroll
      for (int c = 0; c < 8; ++c) {
        xv[2 * c]     = xb[(size_t)(2 * c) * (HI * WI)];
        xv[2 * c + 1] = xb[(size_t)(2 * c + 1) * (HI * WI)];
        rv[2 * c]     = rb[(size_t)(2 * c) * (HO * WO)];
        rv[2 * c + 1] = rb[(size_t)(2 * c + 1) * (HO * WO)];
      }
      if (tid < 128) {
        const int hh = hbase + 2;            // resr slot 3
        if (hh < HO) {
          gk = true;
          const int p = tid >> 1, half = tid & 1;
          gsp = ref + ((size_t)(b * C + half) * HO + hh) * WO + 2 * p;
#pragma unroll
          for (int k = 0; k < 16; ++k)       // batch 1 issue
            g[k] = *(const float2*)&gsp[(size_t)(2 * k) * (HO * WO)];
        }
      }
    }

    // ---- C: conv2 MFMA from refPT (b128 fragments) -------------------------
    f32x4 acc2[4];
#pragma unroll
    for (int t = 0; t < 4; ++t) {
      const int px = wp * 64 + t * 16 + ln;
      const i32x4 b0 = *(const i32x4*)&refPT[px * 36 + lq * 4];
      const i32x4 b1 = *(const i32x4*)&refPT[px * 36 + 16 + lq * 4];
      acc2[t] = (f32x4){0.f, 0.f, 0.f, 0.f};
      acc2[t] = __builtin_amdgcn_mfma_f32_16x16x32_bf16(fb0, __builtin_bit_cast(short8, b0), acc2[t], 0, 0, 0);
      acc2[t] = __builtin_amdgcn_mfma_f32_16x16x32_bf16(fb1, __builtin_bit_cast(short8, b1), acc2[t], 0, 0, 0);
    }
    // conv1 MFMA from xPT -> y1cT (b128 fragments, b128 store per t)
#pragma unroll
    for (int t = 0; t < 4; ++t) {
      const int px = wp * 64 + t * 16 + ln;   // rowsel*64 + col
      const i32x4 b0 = *(const i32x4*)&xPT[px * 36 + lq * 4];
      const i32x4 b1 = *(const i32x4*)&xPT[px * 36 + 16 + lq * 4];
      f32x4 a = {0.f, 0.f, 0.f, 0.f};
      a = __builtin_amdgcn_mfma_f32_16x16x32_bf16(fa0, __builtin_bit_cast(short8, b0), a, 0, 0, 0);
      a = __builtin_amdgcn_mfma_f32_16x16x32_bf16(fa1, __builtin_bit_cast(short8, b1), a, 0, 0, 0);
      f32x4 yv;
#pragma unroll
      for (int r = 0; r < 4; ++r) yv[r] = relu(a[r] + bs1a[r]);
      *(f32x4*)&y1cT[px * 68 + ob] = yv;
    }

    // mask: per-pixel 4 corner weights + den (threads 0..127)
    if (tid < 128) {
      const int w = tid;
      float u9[9];
#pragma unroll
      for (int dh = 0; dh < 3; ++dh)
#pragma unroll
        for (int dw = 0; dw < 3; ++dw) {
          const int col = w + dw - 1;
          u9[dh * 3 + dw] = (col >= 0 && col < 128)
              ? (resr[it + dh][col][0] + resr[it + dh][col][1]) * (1.f / 64.f) : 0.f;
        }
      float sum = u9[0];
#pragma unroll
      for (int k = 1; k < 9; ++k) sum += u9[k];
      const float ua = sum * (1.f / 9.f);
      const bool ui = (u9[4] - ua) > 0.f;

      const int clo = (w >= 1) ? ((w - 1) >> 1) : 0;
      unsigned den = 0;
      unsigned wc0 = 0, wc1 = 0, wc2 = 0, wc3 = 0;
#pragma unroll
      for (int dh = 0; dh < 3; ++dh) {
        const int hh = h + dh - 1;
        const bool hv = (hh >= 0) && (hh < HO);
        const int rs = hv ? ((hh >> 1) - rloc) : 0;
#pragma unroll
        for (int dw = 0; dw < 3; ++dw) {
          const bool up = (u9[dh * 3 + dw] - ua) > 0.f;
          const unsigned mk = (up == ui) ? 1u : 0u;
          den += mk;
          const int ww = w + dw - 1;
          const bool wv = (ww >= 0) && (ww < WO);
          const int cs = wv ? ((ww >> 1) - clo) : 0;
          const unsigned tm = (hv && wv) ? mk : 0u;
          const unsigned t0 = (rs == 0) ? tm : 0u;
          const unsigned t1 = (rs == 1) ? tm : 0u;
          wc0 += (cs == 0) ? t0 : 0u;
          wc1 += (cs == 1) ? t0 : 0u;
          wc2 += (cs == 0) ? t1 : 0u;
          wc3 += (cs == 1) ? t1 : 0u;
        }
      }
      s_wcp[w] = wc0 | (wc1 << 4) | (wc2 << 8) | (wc3 << 12) | (den << 16);
    }
    bar_lds();   // bA: y1cT + mask ready; all xPT/refPT reads complete

    // ---- D: epilogue (b128 corner reads) -----------------------------------
#pragma unroll
    for (int t = 0; t < 4; ++t) {
      const int px = wp * 64 + t * 16 + ln;
      const int cl = (px >= 1) ? ((px - 1) >> 1) : 0;
      int c1 = cl + 1; if (c1 > WI - 1) c1 = WI - 1;
      const unsigned pk = s_wcp[px];
      const float wc0 = (float)(pk & 15u);
      const float wc1 = (float)((pk >> 4) & 15u);
      const float wc2 = (float)((pk >> 8) & 15u);
      const float wc3 = (float)((pk >> 12) & 15u);
      const float inv = 1.f / ((float)((pk >> 16) & 15u) + 1e-6f);

      const f32x4 a00 = *(const f32x4*)&y1cT[cl * 68 + ob];
      const f32x4 a01 = *(const f32x4*)&y1cT[c1 * 68 + ob];
      const f32x4 a10 = *(const f32x4*)&y1cT[(64 + cl) * 68 + ob];
      const f32x4 a11 = *(const f32x4*)&y1cT[(64 + c1) * 68 + ob];

      float* op = out + (size_t)(b * C + ob) * (HO * WO) + h * WO + px;
#pragma unroll
      for (int r = 0; r < 4; ++r) {
        const float n = wc0 * a00[r] + wc1 * a01[r]
                      + wc2 * a10[r] + wc3 * a11[r];
        op[(size_t)r * (HO * WO)] = n * inv + relu(acc2[t][r] + bs2a[r]);
      }
    }

    // ---- E: write prefetched next-row data (same buffers — safe post-bA) ---
    if (it == 0) {
      uint4 u0, u1, v0, v1q;
      u0.x = packbf(xv[0], xv[1]);  u0.y = packbf(xv[2], xv[3]);
      u0.z = packbf(xv[4], xv[5]);  u0.w = packbf(xv[6], xv[7]);
      u1.x = packbf(xv[8], xv[9]);  u1.y = packbf(xv[10], xv[11]);
      u1.z = packbf(xv[12], xv[13]); u1.w = packbf(xv[14], xv[15]);
      v0.x = packbf(rv[0], rv[1]);  v0.y = packbf(rv[2], rv[3]);
      v0.z = packbf(rv[4], rv[5]);  v0.w = packbf(rv[6], rv[7]);
      v1q.x = packbf(rv[8], rv[9]); v1q.y = packbf(rv[10], rv[11]);
      v1q.z = packbf(rv[12], rv[13]); v1q.w = packbf(rv[14], rv[15]);
      *(uint4*)&xPT[spx * 36 + sc2g * 8]       = u0;
      *(uint4*)&xPT[spx * 36 + sc2g * 8 + 4]   = u1;
      *(uint4*)&refPT[spx * 36 + sc2g * 8]     = v0;
      *(uint4*)&refPT[spx * 36 + sc2g * 8 + 4] = v1q;
      if (tid < 128) {
        float sx = 0.f, sy = 0.f;
        if (gk) {                            // sum b1, issue+sum b2 (ascending)
#pragma unroll
          for (int k = 0; k < 16; ++k) { sx += g[k].x; sy += g[k].y; }
#pragma unroll
          for (int k = 0; k < 16; ++k)
            g[k] = *(const float2*)&gsp[(size_t)(2 * (k + 16)) * (HO * WO)];
#pragma unroll
          for (int k = 0; k < 16; ++k) { sx += g[k].x; sy += g[k].y; }
        }
        const int p = tid >> 1, half = tid & 1;
        resr[3][2 * p][half]     = sx;
        resr[3][2 * p + 1][half] = sy;
      }
      bar_lds();   // bB: next-row buffers visible; y1cT/s_wcp reads done
    }
  }
}

// ---------------------------------------------------------------------------
extern "C" void kernel_launch(void* const* d_in, const int* in_sizes, int n_in,
                              void* d_out, int out_size, void* d_ws, size_t ws_size,
                              hipStream_t stream) {
  (void)in_sizes; (void)n_in; (void)out_size; (void)d_ws; (void)ws_size;
  const float* x   = (const float*)d_in[0];
  const float* ref = (const float*)d_in[1];
  const float* w1  = (const float*)d_in[2];
  const float* c1b = (const float*)d_in[3];
  const float* g1  = (const float*)d_in[4];
  const float* b1  = (const float*)d_in[5];
  const float* m1  = (const float*)d_in[6];
  const float* v1  = (const float*)d_in[7];
  const float* w2  = (const float*)d_in[8];
  const float* c2b = (const float*)d_in[9];
  const float* g2  = (const float*)d_in[10];
  const float* b2  = (const float*)d_in[11];
  const float* m2  = (const float*)d_in[12];
  const float* v2  = (const float*)d_in[13];
  float* out = (float*)d_out;

  k_all<<<512, 512, 0, stream>>>(x, ref, w1, c1b, g1, b1, m1, v1,
                                 w2, c2b, g2, b2, m2, v2, out);
}

// Round 10
// 122.807 us; speedup vs baseline: 1.2263x; 1.2263x over previous
//
#include <hip/hip_runtime.h>

// Problem dims (hardcoded per reference setup_inputs):
//   x:   (8, 64, 64, 64)   fp32
//   ref: (8, 64, 128, 128) fp32
//   out: (8, 64, 128, 128) fp32
#define B   8
#define C   64
#define HI  64
#define WI  64
#define HO  128
#define WO  128

using short8 = __attribute__((ext_vector_type(8))) short;
using f32x4  = __attribute__((ext_vector_type(4))) float;
using i32x4  = __attribute__((ext_vector_type(4))) int;

__device__ __forceinline__ float relu(float v) { return v > 0.f ? v : 0.f; }

// pack two f32 -> bf16 pair (lo in bits [15:0], hi in bits [31:16]), RNE
__device__ __forceinline__ unsigned packbf(float lo, float hi) {
  unsigned ua = __float_as_uint(lo); ua += 0x7FFFu + ((ua >> 16) & 1u);
  unsigned ub = __float_as_uint(hi); ub += 0x7FFFu + ((ub >> 16) & 1u);
  return (ua >> 16) | (ub & 0xFFFF0000u);
}

// ---------------------------------------------------------------------------
// Round-10 = measured-best round-6 structure (123.75 us) + nontemporal out
// stores (out is write-once, never re-read -> keep ref rows L2-resident for
// the gather phase instead of churning L2 with the 128 KB/block of output).
//
// Persistent-block pipelined kernel, PIXEL-MAJOR LDS (all hot LDS traffic is
// ds_read_b128/ds_write_b128). 256 blocks (1/CU), 512 threads; each block
// does 4 rows h=hbase..hbase+3 of batch b = bx&7 (XCD-affine).
//
// LDS (115.7 KB, 1 block/CU):
//   y1cT [128 px][68 ch] f32 : conv1 out; b128 write per t, b128 corner reads
//   xPT/refPT [2][128 px][36 c2] u32 bf16-pairs: B-fragment = i32x4 at
//       px*36 + lq*4 (+16) — one b128 instead of 8 scalar b32.
//   resr [6][128][2], rolling gather rows (bit-exact order from round 0).
// Staging ownership is px-major: thread (spx = tid&127, sc2g = tid>>7) loads
// 32 coalesced scalar dwords (held in regs across compute), packs to bf16 and
// writes 4 uint4 ds_writes in E. Same values/orders as before -> bit-exact.
// Pipeline per iteration: A issue next-row loads -> C conv2+conv1 MFMA + mask
// -> bA -> D epilogue -> E pack/write next buffers -> bB.
// ---------------------------------------------------------------------------
__global__ __launch_bounds__(512, 2) void k_all(
    const float* __restrict__ x,   const float* __restrict__ ref,
    const float* __restrict__ w1,  const float* __restrict__ c1b,
    const float* __restrict__ g1,  const float* __restrict__ b1v,
    const float* __restrict__ m1,  const float* __restrict__ v1,
    const float* __restrict__ w2,  const float* __restrict__ c2b,
    const float* __restrict__ g2,  const float* __restrict__ b2v,
    const float* __restrict__ m2,  const float* __restrict__ v2,
    float* __restrict__ out) {
  __shared__ __align__(16) float    y1cT[128 * 68];      // [px][ch]
  __shared__ __align__(16) unsigned xPT[2][128 * 36];    // [px][c2] bf16-pair
  __shared__ __align__(16) unsigned refPT[2][128 * 36];  // [px][c2] bf16-pair
  __shared__ __align__(16) float    resr[6][128][2];     // rolling gather rows
  __shared__ unsigned s_wcp[128];                        // wc0..3 + den nibbles
  __shared__ float    s_bs1[64];
  __shared__ float    s_bs2[64];

  const int bx  = blockIdx.x;
  const int b     = bx & 7;          // XCD-affine batch
  const int hbase = (bx >> 3) * 4;   // 0,4,...,124
  const int tid = threadIdx.x;

  const int wid  = tid >> 6;          // 0..7
  const int lane = tid & 63;
  const int wo = wid & 3, wp = wid >> 2;   // o-tile, px-half
  const int lq = lane >> 4, ln = lane & 15;
  const int ob = wo * 16 + lq * 4;
  const int ow = wo * 16 + ln;        // weight row for A-fragments

  // staging ownership (px-major)
  const int spx  = tid & 127;         // owned px
  const int sc2g = tid >> 7;          // c2 octet: c2 = sc2g*8 + c
  const int scol = spx & 63;          // x column
  const int ssel = spx >> 6;          // x row selector (0 -> rlo, 1 -> r1)

  // ---- weight fragment loads issued first (once per block) -----------------
  const float4 wa0 = *(const float4*)&w1[ow * 64 + lq * 8];
  const float4 wa1 = *(const float4*)&w1[ow * 64 + lq * 8 + 4];
  const float4 wa2 = *(const float4*)&w1[ow * 64 + 32 + lq * 8];
  const float4 wa3 = *(const float4*)&w1[ow * 64 + 32 + lq * 8 + 4];
  const float4 wb0 = *(const float4*)&w2[ow * 64 + lq * 8];
  const float4 wb1 = *(const float4*)&w2[ow * 64 + lq * 8 + 4];
  const float4 wb2 = *(const float4*)&w2[ow * 64 + 32 + lq * 8];
  const float4 wb3 = *(const float4*)&w2[ow * 64 + 32 + lq * 8 + 4];
  const float g1o = g1[ow], v1o = v1[ow];
  const float g2o = g2[ow], v2o = v2[ow];

  // ---------------- prologue: stage row hbase into buffers[0] ---------------
  {
    const int rlo0 = (hbase >= 1) ? ((hbase - 1) >> 1) : 0;
    int r10 = rlo0 + 1; if (r10 > HI - 1) r10 = HI - 1;

    float xv[16], rv[16];
    {
      const int xr = ssel ? r10 : rlo0;
      const float* xb = x + ((size_t)(b * C + sc2g * 16) * HI + xr) * WI + scol;
      const float* rb = ref + ((size_t)(b * C + sc2g * 16) * HO + hbase) * WO + spx;
#pragma unroll
      for (int c = 0; c < 8; ++c) {
        xv[2 * c]     = xb[(size_t)(2 * c) * (HI * WI)];
        xv[2 * c + 1] = xb[(size_t)(2 * c + 1) * (HI * WI)];
        rv[2 * c]     = rb[(size_t)(2 * c) * (HO * WO)];
        rv[2 * c + 1] = rb[(size_t)(2 * c + 1) * (HO * WO)];
      }
    }
    // gather rows hbase-1..hbase+1 -> slots 0..2 (threads 0..383, 1 chain ea.)
    float2 pg[32];
    const int grr = tid >> 7;
    const int gp = (tid & 127) >> 1, ghalf = tid & 1;
    bool gok = false;
    if (tid < 384) {
      const int hh = hbase + grr - 1;
      if (hh >= 0 && hh < HO) {
        gok = true;
        const float* sp = ref + ((size_t)(b * C + ghalf) * HO + hh) * WO + 2 * gp;
#pragma unroll
        for (int k = 0; k < 32; ++k)
          pg[k] = *(const float2*)&sp[(size_t)(2 * k) * (HO * WO)];
      }
    }
    if (tid >= 448) {                        // biases (threads 448..511)
      const int t2 = tid - 448;
      float s = g1[t2] * rsqrtf(v1[t2] + 1e-5f);
      s_bs1[t2] = c1b[t2] * s + b1v[t2] - m1[t2] * s;
      s = g2[t2] * rsqrtf(v2[t2] + 1e-5f);
      s_bs2[t2] = c2b[t2] * s + b2v[t2] - m2[t2] * s;
    }
    {
      uint4 u0, u1, v0, v1q;
      u0.x = packbf(xv[0], xv[1]);  u0.y = packbf(xv[2], xv[3]);
      u0.z = packbf(xv[4], xv[5]);  u0.w = packbf(xv[6], xv[7]);
      u1.x = packbf(xv[8], xv[9]);  u1.y = packbf(xv[10], xv[11]);
      u1.z = packbf(xv[12], xv[13]); u1.w = packbf(xv[14], xv[15]);
      v0.x = packbf(rv[0], rv[1]);  v0.y = packbf(rv[2], rv[3]);
      v0.z = packbf(rv[4], rv[5]);  v0.w = packbf(rv[6], rv[7]);
      v1q.x = packbf(rv[8], rv[9]); v1q.y = packbf(rv[10], rv[11]);
      v1q.z = packbf(rv[12], rv[13]); v1q.w = packbf(rv[14], rv[15]);
      *(uint4*)&xPT[0][spx * 36 + sc2g * 8]       = u0;
      *(uint4*)&xPT[0][spx * 36 + sc2g * 8 + 4]   = u1;
      *(uint4*)&refPT[0][spx * 36 + sc2g * 8]     = v0;
      *(uint4*)&refPT[0][spx * 36 + sc2g * 8 + 4] = v1q;
    }
    if (tid < 384) {                         // sum (ascending, bit-exact) + store
      float sx = 0.f, sy = 0.f;
      if (gok) {
#pragma unroll
        for (int k = 0; k < 32; ++k) { sx += pg[k].x; sy += pg[k].y; }
      }
      resr[grr][2 * gp][ghalf]     = sx;
      resr[grr][2 * gp + 1][ghalf] = sy;
    }
  }

  // pack weight fragments (loads long since landed)
  i32x4 fa0i, fa1i, fb0i, fb1i;
  {
    const float s1 = g1o * rsqrtf(v1o + 1e-5f);
    const float s2 = g2o * rsqrtf(v2o + 1e-5f);
    fa0i[0] = (int)packbf(wa0.x * s1, wa0.y * s1);
    fa0i[1] = (int)packbf(wa0.z * s1, wa0.w * s1);
    fa0i[2] = (int)packbf(wa1.x * s1, wa1.y * s1);
    fa0i[3] = (int)packbf(wa1.z * s1, wa1.w * s1);
    fa1i[0] = (int)packbf(wa2.x * s1, wa2.y * s1);
    fa1i[1] = (int)packbf(wa2.z * s1, wa2.w * s1);
    fa1i[2] = (int)packbf(wa3.x * s1, wa3.y * s1);
    fa1i[3] = (int)packbf(wa3.z * s1, wa3.w * s1);
    fb0i[0] = (int)packbf(wb0.x * s2, wb0.y * s2);
    fb0i[1] = (int)packbf(wb0.z * s2, wb0.w * s2);
    fb0i[2] = (int)packbf(wb1.x * s2, wb1.y * s2);
    fb0i[3] = (int)packbf(wb1.z * s2, wb1.w * s2);
    fb1i[0] = (int)packbf(wb2.x * s2, wb2.y * s2);
    fb1i[1] = (int)packbf(wb2.z * s2, wb2.w * s2);
    fb1i[2] = (int)packbf(wb3.x * s2, wb3.y * s2);
    fb1i[3] = (int)packbf(wb3.z * s2, wb3.w * s2);
  }
  const short8 fa0 = __builtin_bit_cast(short8, fa0i);
  const short8 fa1 = __builtin_bit_cast(short8, fa1i);
  const short8 fb0 = __builtin_bit_cast(short8, fb0i);
  const short8 fb1 = __builtin_bit_cast(short8, fb1i);
  __syncthreads();   // prologue barrier

  float bs1a[4], bs2a[4];
  *(float4*)bs1a = *(const float4*)&s_bs1[ob];
  *(float4*)bs2a = *(const float4*)&s_bs2[ob];

  // ---------------- 4-row pipeline ------------------------------------------
#pragma unroll
  for (int it = 0; it < 4; ++it) {
    const int cur = it & 1, nxt = cur ^ 1;
    const int h = hbase + it;
    const int rloc = (h >= 1) ? ((h - 1) >> 1) : 0;

    // ---- A: issue next row's loads into regs -------------------------------
    float xv[16], rv[16];
    float2 g[32];
    bool gk = false;
    if (it < 3) {
      const int hn = h + 1;
      const int rlon = (hn - 1) >> 1;
      int r1n = rlon + 1; if (r1n > HI - 1) r1n = HI - 1;
      const int xr = ssel ? r1n : rlon;
      const float* xb = x + ((size_t)(b * C + sc2g * 16) * HI + xr) * WI + scol;
      const float* rb = ref + ((size_t)(b * C + sc2g * 16) * HO + hn) * WO + spx;
#pragma unroll
      for (int c = 0; c < 8; ++c) {
        xv[2 * c]     = xb[(size_t)(2 * c) * (HI * WI)];
        xv[2 * c + 1] = xb[(size_t)(2 * c + 1) * (HI * WI)];
        rv[2 * c]     = rb[(size_t)(2 * c) * (HO * WO)];
        rv[2 * c + 1] = rb[(size_t)(2 * c + 1) * (HO * WO)];
      }
      if (tid < 128) {
        const int hh = hbase + it + 2;       // resr slot it+3
        if (hh < HO) {
          gk = true;
          const int p = tid >> 1, half = tid & 1;
          const float* sp = ref + ((size_t)(b * C + half) * HO + hh) * WO + 2 * p;
#pragma unroll
          for (int k = 0; k < 32; ++k)
            g[k] = *(const float2*)&sp[(size_t)(2 * k) * (HO * WO)];
        }
      }
    }

    // ---- C: conv2 MFMA from refPT[cur] (b128 fragments) --------------------
    f32x4 acc2[4];
#pragma unroll
    for (int t = 0; t < 4; ++t) {
      const int px = wp * 64 + t * 16 + ln;
      const i32x4 b0 = *(const i32x4*)&refPT[cur][px * 36 + lq * 4];
      const i32x4 b1 = *(const i32x4*)&refPT[cur][px * 36 + 16 + lq * 4];
      acc2[t] = (f32x4){0.f, 0.f, 0.f, 0.f};
      acc2[t] = __builtin_amdgcn_mfma_f32_16x16x32_bf16(fb0, __builtin_bit_cast(short8, b0), acc2[t], 0, 0, 0);
      acc2[t] = __builtin_amdgcn_mfma_f32_16x16x32_bf16(fb1, __builtin_bit_cast(short8, b1), acc2[t], 0, 0, 0);
    }
    // conv1 MFMA from xPT[cur] -> y1cT (b128 fragments, b128 store per t)
#pragma unroll
    for (int t = 0; t < 4; ++t) {
      const int px = wp * 64 + t * 16 + ln;   // rowsel*64 + col
      const i32x4 b0 = *(const i32x4*)&xPT[cur][px * 36 + lq * 4];
      const i32x4 b1 = *(const i32x4*)&xPT[cur][px * 36 + 16 + lq * 4];
      f32x4 a = {0.f, 0.f, 0.f, 0.f};
      a = __builtin_amdgcn_mfma_f32_16x16x32_bf16(fa0, __builtin_bit_cast(short8, b0), a, 0, 0, 0);
      a = __builtin_amdgcn_mfma_f32_16x16x32_bf16(fa1, __builtin_bit_cast(short8, b1), a, 0, 0, 0);
      f32x4 yv;
#pragma unroll
      for (int r = 0; r < 4; ++r) yv[r] = relu(a[r] + bs1a[r]);
      *(f32x4*)&y1cT[px * 68 + ob] = yv;
    }

    // mask: per-pixel 4 corner weights + den (threads 0..127)
    if (tid < 128) {
      const int w = tid;
      float u9[9];
#pragma unroll
      for (int dh = 0; dh < 3; ++dh)
#pragma unroll
        for (int dw = 0; dw < 3; ++dw) {
          const int col = w + dw - 1;
          u9[dh * 3 + dw] = (col >= 0 && col < 128)
              ? (resr[it + dh][col][0] + resr[it + dh][col][1]) * (1.f / 64.f) : 0.f;
        }
      float sum = u9[0];
#pragma unroll
      for (int k = 1; k < 9; ++k) sum += u9[k];
      const float ua = sum * (1.f / 9.f);
      const bool ui = (u9[4] - ua) > 0.f;

      const int clo = (w >= 1) ? ((w - 1) >> 1) : 0;
      unsigned den = 0;
      unsigned wc0 = 0, wc1 = 0, wc2 = 0, wc3 = 0;
#pragma unroll
      for (int dh = 0; dh < 3; ++dh) {
        const int hh = h + dh - 1;
        const bool hv = (hh >= 0) && (hh < HO);
        const int rs = hv ? ((hh >> 1) - rloc) : 0;
#pragma unroll
        for (int dw = 0; dw < 3; ++dw) {
          const bool up = (u9[dh * 3 + dw] - ua) > 0.f;
          const unsigned mk = (up == ui) ? 1u : 0u;
          den += mk;
          const int ww = w + dw - 1;
          const bool wv = (ww >= 0) && (ww < WO);
          const int cs = wv ? ((ww >> 1) - clo) : 0;
          const unsigned tm = (hv && wv) ? mk : 0u;
          const unsigned t0 = (rs == 0) ? tm : 0u;
          const unsigned t1 = (rs == 1) ? tm : 0u;
          wc0 += (cs == 0) ? t0 : 0u;
          wc1 += (cs == 1) ? t0 : 0u;
          wc2 += (cs == 0) ? t1 : 0u;
          wc3 += (cs == 1) ? t1 : 0u;
        }
      }
      s_wcp[w] = wc0 | (wc1 << 4) | (wc2 << 8) | (wc3 << 12) | (den << 16);
    }
    __syncthreads();   // bA: y1cT + mask ready (also drains prefetch loads)

    // ---- D: epilogue (b128 corner reads; nontemporal out stores) -----------
#pragma unroll
    for (int t = 0; t < 4; ++t) {
      const int px = wp * 64 + t * 16 + ln;
      const int cl = (px >= 1) ? ((px - 1) >> 1) : 0;
      int c1 = cl + 1; if (c1 > WI - 1) c1 = WI - 1;
      const unsigned pk = s_wcp[px];
      const float wc0 = (float)(pk & 15u);
      const float wc1 = (float)((pk >> 4) & 15u);
      const float wc2 = (float)((pk >> 8) & 15u);
      const float wc3 = (float)((pk >> 12) & 15u);
      const float inv = 1.f / ((float)((pk >> 16) & 15u) + 1e-6f);

      const f32x4 a00 = *(const f32x4*)&y1cT[cl * 68 + ob];
      const f32x4 a01 = *(const f32x4*)&y1cT[c1 * 68 + ob];
      const f32x4 a10 = *(const f32x4*)&y1cT[(64 + cl) * 68 + ob];
      const f32x4 a11 = *(const f32x4*)&y1cT[(64 + c1) * 68 + ob];

      float* op = out + (size_t)(b * C + ob) * (HO * WO) + h * WO + px;
#pragma unroll
      for (int r = 0; r < 4; ++r) {
        const float n = wc0 * a00[r] + wc1 * a01[r]
                      + wc2 * a10[r] + wc3 * a11[r];
        __builtin_nontemporal_store(n * inv + relu(acc2[t][r] + bs2a[r]),
                                    &op[(size_t)r * (HO * WO)]);
      }
    }

    // ---- E: write prefetched next-row data ---------------------------------
    if (it < 3) {
      uint4 u0, u1, v0, v1q;
      u0.x = packbf(xv[0], xv[1]);  u0.y = packbf(xv[2], xv[3]);
      u0.z = packbf(xv[4], xv[5]);  u0.w = packbf(xv[6], xv[7]);
      u1.x = packbf(xv[8], xv[9]);  u1.y = packbf(xv[10], xv[11]);
      u1.z = packbf(xv[12], xv[13]); u1.w = packbf(xv[14], xv[15]);
      v0.x = packbf(rv[0], rv[1]);  v0.y = packbf(rv[2], rv[3]);
      v0.z = packbf(rv[4], rv[5]);  v0.w = packbf(rv[6], rv[7]);
      v1q.x = packbf(rv[8], rv[9]); v1q.y = packbf(rv[10], rv[11]);
      v1q.z = packbf(rv[12], rv[13]); v1q.w = packbf(rv[14], rv[15]);
      *(uint4*)&xPT[nxt][spx * 36 + sc2g * 8]       = u0;
      *(uint4*)&xPT[nxt][spx * 36 + sc2g * 8 + 4]   = u1;
      *(uint4*)&refPT[nxt][spx * 36 + sc2g * 8]     = v0;
      *(uint4*)&refPT[nxt][spx * 36 + sc2g * 8 + 4] = v1q;
      if (tid < 128) {
        float sx = 0.f, sy = 0.f;
        if (gk) {
#pragma unroll
          for (int k = 0; k < 32; ++k) { sx += g[k].x; sy += g[k].y; }
        }
        const int p = tid >> 1, half = tid & 1;
        resr[it + 3][2 * p][half]     = sx;
        resr[it + 3][2 * p + 1][half] = sy;
      }
      __syncthreads();   // bB: next-row buffers visible; y1cT/s_wcp reads done
    }
  }
}

// ---------------------------------------------------------------------------
extern "C" void kernel_launch(void* const* d_in, const int* in_sizes, int n_in,
                              void* d_out, int out_size, void* d_ws, size_t ws_size,
                              hipStream_t stream) {
  (void)in_sizes; (void)n_in; (void)out_size; (void)d_ws; (void)ws_size;
  const float* x   = (const float*)d_in[0];
  const float* ref = (const float*)d_in[1];
  const float* w1  = (const float*)d_in[2];
  const float* c1b = (const float*)d_in[3];
  const float* g1  = (const float*)d_in[4];
  const float* b1  = (const float*)d_in[5];
  const float* m1  = (const float*)d_in[6];
  const float* v1  = (const float*)d_in[7];
  const float* w2  = (const float*)d_in[8];
  const float* c2b = (const float*)d_in[9];
  const float* g2  = (const float*)d_in[10];
  const float* b2  = (const float*)d_in[11];
  const float* m2  = (const float*)d_in[12];
  const float* v2  = (const float*)d_in[13];
  float* out = (float*)d_out;

  k_all<<<256, 512, 0, stream>>>(x, ref, w1, c1b, g1, b1, m1, v1,
                                 w2, c2b, g2, b2, m2, v2, out);
}